// Round 5
// baseline (1932.244 us; speedup 1.0000x reference)
//
#include <hip/hip_runtime.h>
#include <hip/hip_fp16.h>

typedef unsigned int uint;
typedef unsigned short ushort;
typedef unsigned long long ull;

#define B 16
#define N 4096
#define S 1024          // NPOINT
#define K 32            // NSAMPLE
#define NPOS (B*S*K)    // 524288
#define NPAIR (NPOS/2)  // 262144

__device__ inline float h2f(ushort b) {
    __half h; *(ushort*)&h = b; return __half2float(h);
}
__device__ inline ushort f2h(float v) {
    __half h = __float2half(v); return *(ushort*)&h;
}

// ---- fused FPS (blocks 0..15) + feature transpose (blocks 16..527) ----
// FPS: 512 threads, 8 pts/thread in registers; packed-u64 (dist,~j) argmax;
// DPP wave reduction (row_shr 1,2,4,8 + row_bcast 15,31 -> lane 63), one
// atomicMax per wave into 3-slot rotating LDS u64, ONE barrier per step.
// Transpose: (B,64,N) -> (B,N,64), two 64x64 tiles per block, aliases lc.
__global__ __launch_bounds__(512) void fps_tr_kernel(const float* __restrict__ xyz,
                                                     float* __restrict__ new_xyz,
                                                     const float* __restrict__ feat,
                                                     float* __restrict__ featT) {
    __shared__ float4 lc[N];      // 64 KB
    __shared__ ull slot[3];
    const int lt = threadIdx.x;   // 0..511

    if (blockIdx.x >= 16) {
        // ---------- transpose path ----------
        float* tile = (float*)lc;             // 2 * 64*65 floats = 33 KB
        const int tb = blockIdx.x - 16;       // 0..511
        const int b  = tb >> 5;               // batch
        const int nb = (tb & 31) << 7;        // 128-col chunk
        const int h  = lt >> 8;               // half: 0/1
        const int tt = lt & 255;
        const int tn = tt & 63;
        const int r  = tt >> 6;               // 0..3
        float* mytile = tile + h * (64 * 65);
        const int n0 = nb + (h << 6);
        for (int c = r; c < 64; c += 4)
            mytile[c * 65 + tn] = feat[((size_t)b * 64 + c) * N + n0 + tn];
        __syncthreads();
        for (int n = r; n < 64; n += 4)
            featT[((size_t)b * N + n0 + n) * 64 + tn] = mytile[tn * 65 + n];
        return;
    }

    // ---------- FPS path ----------
    const int b = blockIdx.x;
    const float* xb = xyz + (size_t)b * N * 3;
    float px[8], py[8], pz[8], dist[8];
    uint njc[8];
    #pragma unroll
    for (int p = 0; p < 8; ++p) {
        const int j = lt + (p << 9);
        float x = xb[j*3+0], y = xb[j*3+1], z = xb[j*3+2];
        lc[j] = make_float4(x, y, z, 0.f);
        px[p] = x; py[p] = y; pz[p] = z;
        dist[p] = 1e10f;
        njc[p] = ~(uint)j;
    }
    if (lt < 3) slot[lt] = 0ull;
    __syncthreads();

    float4 c0 = lc[0];
    float cx = c0.x, cy = c0.y, cz = c0.z;
    float* outb = new_xyz + (size_t)b * S * 3;

    int cur = 0;
    for (int s = 0; s < S; ++s) {
        if (lt == 0) { outb[s*3+0] = cx; outb[s*3+1] = cy; outb[s*3+2] = cz; }

        ull best = 0ull;
        #pragma unroll
        for (int p = 0; p < 8; ++p) {
            float dx = px[p] - cx, dy = py[p] - cy, dz = pz[p] - cz;
            float d  = __fadd_rn(__fadd_rn(__fmul_rn(dx,dx), __fmul_rn(dy,dy)), __fmul_rn(dz,dz));
            float nd = fminf(dist[p], d);
            dist[p] = nd;
            ull pk = ((ull)__float_as_uint(nd) << 32) | (ull)njc[p];
            if (pk > best) best = pk;
        }
        // DPP wave-64 max reduction -> lane 63 (VALU pipe, no LDS latency)
        {
            uint hi = (uint)(best >> 32), lo = (uint)best;
            #define FPS_DPP(CTRL) { \
                uint h2 = (uint)__builtin_amdgcn_update_dpp((int)hi, (int)hi, CTRL, 0xF, 0xF, false); \
                uint l2 = (uint)__builtin_amdgcn_update_dpp((int)lo, (int)lo, CTRL, 0xF, 0xF, false); \
                ull o = ((ull)h2 << 32) | (ull)l2; \
                if (o > best) { best = o; hi = h2; lo = l2; } }
            FPS_DPP(0x111)   // row_shr:1
            FPS_DPP(0x112)   // row_shr:2
            FPS_DPP(0x114)   // row_shr:4
            FPS_DPP(0x118)   // row_shr:8
            FPS_DPP(0x142)   // row_bcast:15
            FPS_DPP(0x143)   // row_bcast:31
            #undef FPS_DPP
        }
        if ((lt & 63) == 63) atomicMax(&slot[cur], best);
        int nxt = cur + 1; if (nxt == 3) nxt = 0;
        if (lt == 0) slot[nxt] = 0ull;   // slot last read 2 barriers ago (safe)
        __syncthreads();
        ull pk = slot[cur];
        int last = (int)(~(uint)pk);     // lo32 = ~j exactly
        float4 c4 = lc[last];
        cx = c4.x; cy = c4.y; cz = c4.z;
        cur = nxt;
    }
}

// ---------------- ball query: one wave per center ----------------
__global__ __launch_bounds__(256) void ballq_kernel(const float* __restrict__ xyz,
                                                    const float* __restrict__ new_xyz,
                                                    int* __restrict__ idx) {
    const int wid  = (blockIdx.x * 256 + threadIdx.x) >> 6;   // center id
    const int lane = threadIdx.x & 63;
    const int b = wid >> 10;
    const float* xb = xyz + (size_t)b * N * 3;
    const float cx = new_xyz[(size_t)wid*3+0];
    const float cy = new_xyz[(size_t)wid*3+1];
    const float cz = new_xyz[(size_t)wid*3+2];
    int* ob = idx + (size_t)wid * K;

    const float R2 = 0.04f;  // float32(0.2*0.2) per JAX weak-type demotion
    int total = 0;
    int first = 0;
    bool gotfirst = false;
    for (int c0 = 0; c0 < N; c0 += 64) {
        const int j = c0 + lane;
        float dx = cx - xb[j*3+0];
        float dy = cy - xb[j*3+1];
        float dz = cz - xb[j*3+2];
        float d2 = __fadd_rn(__fadd_rn(__fmul_rn(dx,dx), __fmul_rn(dy,dy)), __fmul_rn(dz,dz));
        bool inr = d2 < R2;
        unsigned long long bal = __ballot(inr);
        if (bal) {
            if (!gotfirst) { first = c0 + __builtin_ctzll(bal); gotfirst = true; }
            int rank = __popcll(bal & ((1ull << lane) - 1ull));
            int pos = total + rank;
            if (inr && pos < K) ob[pos] = j;
            total += __popcll(bal);
            if (total >= K) break;
        }
    }
    for (int p2 = total + lane; p2 < K; p2 += 64) ob[p2] = first;
}

// ---------------- conv0: gather + 67->64, store fp16 channel-major ----------------
__global__ __launch_bounds__(256) void conv0_kernel(const float* __restrict__ xyz,
                                                    const float* __restrict__ new_xyz,
                                                    const float* __restrict__ featT,
                                                    const int* __restrict__ idx,
                                                    const float* __restrict__ w0,
                                                    const float* __restrict__ b0,
                                                    ushort* __restrict__ x0) {
    const int p  = blockIdx.x * 256 + threadIdx.x;  // position
    const int bs = p >> 5;                          // b*S+s
    const int b  = p >> 15;
    const int j  = idx[p];

    float fin[67];
    {
        const float* xp = xyz + ((size_t)b*N + (size_t)j)*3;
        fin[0] = xp[0] - new_xyz[(size_t)bs*3+0];
        fin[1] = xp[1] - new_xyz[(size_t)bs*3+1];
        fin[2] = xp[2] - new_xyz[(size_t)bs*3+2];
        const float4* fr = (const float4*)(featT + (((size_t)b*N + j) << 6));
        #pragma unroll
        for (int i = 0; i < 16; ++i) {
            float4 v = fr[i];
            fin[3+4*i] = v.x; fin[4+4*i] = v.y; fin[5+4*i] = v.z; fin[6+4*i] = v.w;
        }
    }
    #pragma unroll
    for (int og = 0; og < 64; og += 8) {
        float a[8];
        #pragma unroll
        for (int i = 0; i < 8; ++i) a[i] = b0[og+i];
        #pragma unroll
        for (int c = 0; c < 67; ++c) {
            float xv = fin[c];
            #pragma unroll
            for (int i = 0; i < 8; ++i)
                a[i] = fmaf(w0[(size_t)(og+i)*67 + c], xv, a[i]);
        }
        #pragma unroll
        for (int i = 0; i < 8; ++i)
            x0[(size_t)(og+i)*NPOS + p] = f2h(a[i]);
    }
}

// ---------------- per-channel sum / sumsq (C=64 layout, stride 64) ----------------
__global__ __launch_bounds__(256) void stats_kernel(const ushort* __restrict__ x,
                                                    float* __restrict__ st) {
    const int c = blockIdx.y;   // 0..63
    const uint2* xr = (const uint2*)(x + (size_t)c * NPOS);
    const int t = blockIdx.x * 256 + threadIdx.x;   // 0..8191
    float s = 0.f, q = 0.f;
    #pragma unroll
    for (int i = 0; i < 16; ++i) {
        uint2 u = xr[(size_t)i*8192 + t];
        float v0 = h2f((ushort)(u.x & 0xffff));
        float v1 = h2f((ushort)(u.x >> 16));
        float v2 = h2f((ushort)(u.y & 0xffff));
        float v3 = h2f((ushort)(u.y >> 16));
        s += v0 + v1 + v2 + v3;
        q += v0*v0 + v1*v1 + v2*v2 + v3*v3;
    }
    #pragma unroll
    for (int off = 32; off; off >>= 1) { s += __shfl_xor(s, off); q += __shfl_xor(q, off); }
    __shared__ float ls[4], lq[4];
    const int w = threadIdx.x >> 6;
    if ((threadIdx.x & 63) == 0) { ls[w] = s; lq[w] = q; }
    __syncthreads();
    if (threadIdx.x == 0) {
        s = ls[0]+ls[1]+ls[2]+ls[3];
        q = lq[0]+lq[1]+lq[2]+lq[3];
        atomicAdd(&st[c], s);
        atomicAdd(&st[64+c], q);
    }
}

// ---------------- fold BN into scale/shift (C=64) ----------------
__global__ void finalize_kernel(float* st, const float* __restrict__ g,
                                const float* __restrict__ be) {
    const int c = threadIdx.x;
    if (c < 64) {
        const float invn = 1.0f / (float)NPOS;
        float mean = st[c] * invn;
        float var  = st[64+c] * invn - mean*mean;
        float inv  = 1.0f / sqrtf(var + 1e-5f);
        float sc   = g[c] * inv;
        st[128+c] = sc;
        st[192+c] = fmaf(-mean, sc, be[c]);
    }
}

// ---------------- middle conv: normalize(prev)+relu then 64->64 ----------------
__global__ __launch_bounds__(256) void conv_mid_kernel(const ushort* __restrict__ xin,
                                                       const float* __restrict__ st,   // prev layer stats
                                                       const float* __restrict__ w,
                                                       const float* __restrict__ bias,
                                                       ushort* __restrict__ xout,
                                                       int wbase) {
    const int pp = blockIdx.x * 256 + threadIdx.x;   // pair index < NPAIR
    const float* scale = st + 128;
    const float* shift = st + 192;
    float a0[64], a1[64];
    #pragma unroll
    for (int o = 0; o < 64; ++o) { a0[o] = bias[wbase+o]; a1[o] = a0[o]; }
    const uint* xr = (const uint*)xin;
    #pragma unroll 4
    for (int c = 0; c < 64; ++c) {
        uint u = xr[(size_t)c * NPAIR + pp];
        float v0 = h2f((ushort)(u & 0xffff));
        float v1 = h2f((ushort)(u >> 16));
        float sc = scale[c], sh = shift[c];
        v0 = fmaxf(0.0f, fmaf(v0, sc, sh));
        v1 = fmaxf(0.0f, fmaf(v1, sc, sh));
        const float* wr = w + (size_t)wbase * 64 + c;
        #pragma unroll
        for (int o = 0; o < 64; ++o) {
            float wv = wr[o*64];
            a0[o] = fmaf(wv, v0, a0[o]);
            a1[o] = fmaf(wv, v1, a1[o]);
        }
    }
    uint* orow = (uint*)xout;
    #pragma unroll
    for (int o = 0; o < 64; ++o) {
        uint wd = (uint)f2h(a0[o]) | ((uint)f2h(a1[o]) << 16);
        orow[(size_t)o * NPAIR + pp] = wd;
    }
}

// ---------------- max-pool over K with BN+relu (64-channel half) ----------------
__global__ __launch_bounds__(256) void maxpool_kernel(const ushort* __restrict__ xh,
                                                      const float* __restrict__ st,   // this half's stats
                                                      float* __restrict__ out,
                                                      int cbase) {
    const int gid = blockIdx.x * 256 + threadIdx.x;   // < 64*16384
    const int c  = gid >> 14;       // 0..63 local channel
    const int bs = gid & 16383;
    const float sc = st[128 + c], sh = st[192 + c];
    const uint* xr = (const uint*)(xh + (size_t)c * NPOS + (size_t)bs * K);
    float m = -3.4e38f;
    #pragma unroll
    for (int i = 0; i < 16; ++i) {
        uint u = xr[i];
        m = fmaxf(m, fmaf(h2f((ushort)(u & 0xffff)), sc, sh));
        m = fmaxf(m, fmaf(h2f((ushort)(u >> 16)),    sc, sh));
    }
    m = fmaxf(m, 0.0f);   // relu(max) == max(relu) (monotone)
    const int b = bs >> 10, s = bs & 1023;
    out[((size_t)b*128 + cbase + c)*1024 + s] = m;
}

extern "C" void kernel_launch(void* const* d_in, const int* in_sizes, int n_in,
                              void* d_out, int out_size, void* d_ws, size_t ws_size,
                              hipStream_t stream) {
    const float* xyz      = (const float*)d_in[0];
    const float* features = (const float*)d_in[1];
    const float* w0 = (const float*)d_in[2];
    const float* b0 = (const float*)d_in[3];
    const float* g0 = (const float*)d_in[4];
    const float* be0= (const float*)d_in[5];
    const float* w1 = (const float*)d_in[6];
    const float* b1 = (const float*)d_in[7];
    const float* g1 = (const float*)d_in[8];
    const float* be1= (const float*)d_in[9];
    const float* w2 = (const float*)d_in[10];
    const float* b2 = (const float*)d_in[11];
    const float* g2 = (const float*)d_in[12];
    const float* be2= (const float*)d_in[13];

    float* out      = (float*)d_out;
    float* new_xyz  = out;              // (B,S,3)
    float* new_feat = out + (size_t)B*S*3;

    // Workspace layout (peak ~146 MB):
    //   [0,2MB)      idx
    //   [2,18MB)     featT
    //   [18MB,+4KB)  stats (4 regions x 256 floats)
    //   [A: 64MB)    x0, later reused as x2-half buffer
    //   [Bf: 64MB)   x1
    char* ws = (char*)d_ws;
    int*    idx   = (int*)ws;
    float*  featT = (float*)(ws + (2u<<20));
    float*  stats = (float*)(ws + (18u<<20));
    ushort* x0    = (ushort*)(ws + (18u<<20) + (1u<<16));
    ushort* x1    = x0 + (size_t)64 * NPOS;       // +64MB
    ushort* xh    = x0;                           // layer-2 half buffer aliases x0
    float* st0  = stats;            // C=64: sum,sumsq,scale,shift
    float* st1  = stats + 256;
    float* st2a = stats + 512;
    float* st2b = stats + 768;

    hipMemsetAsync(stats, 0, 1024 * sizeof(float), stream);

    fps_tr_kernel<<<16 + 512, 512, 0, stream>>>(xyz, new_xyz, features, featT);
    ballq_kernel<<<(B*S)/4, 256, 0, stream>>>(xyz, new_xyz, idx);
    conv0_kernel<<<NPOS/256, 256, 0, stream>>>(xyz, new_xyz, featT, idx, w0, b0, x0);

    stats_kernel<<<dim3(32, 64), 256, 0, stream>>>(x0, st0);
    finalize_kernel<<<1, 64, 0, stream>>>(st0, g0, be0);
    conv_mid_kernel<<<NPAIR/256, 256, 0, stream>>>(x0, st0, w1, b1, x1, 0);

    stats_kernel<<<dim3(32, 64), 256, 0, stream>>>(x1, st1);
    finalize_kernel<<<1, 64, 0, stream>>>(st1, g1, be1);

    // layer 2, half 0 (output channels 0..63) — xh aliases x0 (dead now)
    conv_mid_kernel<<<NPAIR/256, 256, 0, stream>>>(x1, st1, w2, b2, xh, 0);
    stats_kernel<<<dim3(32, 64), 256, 0, stream>>>(xh, st2a);
    finalize_kernel<<<1, 64, 0, stream>>>(st2a, g2, be2);
    maxpool_kernel<<<(64*B*S)/256, 256, 0, stream>>>(xh, st2a, new_feat, 0);

    // layer 2, half 1 (output channels 64..127)
    conv_mid_kernel<<<NPAIR/256, 256, 0, stream>>>(x1, st1, w2, b2, xh, 64);
    stats_kernel<<<dim3(32, 64), 256, 0, stream>>>(xh, st2b);
    finalize_kernel<<<1, 64, 0, stream>>>(st2b, g2 + 64, be2 + 64);
    maxpool_kernel<<<(64*B*S)/256, 256, 0, stream>>>(xh, st2b, new_feat, 64);
}

// Round 6
// 1319.863 us; speedup vs baseline: 1.4640x; 1.4640x over previous
//
#include <hip/hip_runtime.h>
#include <hip/hip_fp16.h>

typedef unsigned int uint;
typedef unsigned short ushort;
typedef unsigned long long ull;

#define B 16
#define N 4096
#define S 1024          // NPOINT
#define K 32            // NSAMPLE
#define NPOS (B*S*K)    // 524288
#define NPAIR (NPOS/2)  // 262144

__device__ inline float h2f(ushort b) {
    __half h; *(ushort*)&h = b; return __half2float(h);
}
__device__ inline ushort f2h(float v) {
    __half h = __float2half(v); return *(ushort*)&h;
}

// ---- fused FPS (blocks 0..15) + feature transpose (blocks 16..527) ----
__global__ __launch_bounds__(512) void fps_tr_kernel(const float* __restrict__ xyz,
                                                     float* __restrict__ new_xyz,
                                                     const float* __restrict__ feat,
                                                     float* __restrict__ featT) {
    __shared__ float4 lc[N];      // 64 KB
    __shared__ ull slot[3];
    const int lt = threadIdx.x;   // 0..511

    if (blockIdx.x >= 16) {
        // ---------- transpose path ----------
        float* tile = (float*)lc;             // 2 * 64*65 floats = 33 KB
        const int tb = blockIdx.x - 16;       // 0..511
        const int b  = tb >> 5;               // batch
        const int nb = (tb & 31) << 7;        // 128-col chunk
        const int h  = lt >> 8;               // half: 0/1
        const int tt = lt & 255;
        const int tn = tt & 63;
        const int r  = tt >> 6;               // 0..3
        float* mytile = tile + h * (64 * 65);
        const int n0 = nb + (h << 6);
        for (int c = r; c < 64; c += 4)
            mytile[c * 65 + tn] = feat[((size_t)b * 64 + c) * N + n0 + tn];
        __syncthreads();
        for (int n = r; n < 64; n += 4)
            featT[((size_t)b * N + n0 + n) * 64 + tn] = mytile[tn * 65 + n];
        return;
    }

    // ---------- FPS path ----------
    const int b = blockIdx.x;
    const float* xb = xyz + (size_t)b * N * 3;
    float px[8], py[8], pz[8], dist[8];
    uint njc[8];
    #pragma unroll
    for (int p = 0; p < 8; ++p) {
        const int j = lt + (p << 9);
        float x = xb[j*3+0], y = xb[j*3+1], z = xb[j*3+2];
        lc[j] = make_float4(x, y, z, 0.f);
        px[p] = x; py[p] = y; pz[p] = z;
        dist[p] = 1e10f;
        njc[p] = ~(uint)j;
    }
    if (lt < 3) slot[lt] = 0ull;
    __syncthreads();

    float4 c0 = lc[0];
    float cx = c0.x, cy = c0.y, cz = c0.z;
    float* outb = new_xyz + (size_t)b * S * 3;

    int cur = 0;
    for (int s = 0; s < S; ++s) {
        if (lt == 0) { outb[s*3+0] = cx; outb[s*3+1] = cy; outb[s*3+2] = cz; }

        ull best = 0ull;
        #pragma unroll
        for (int p = 0; p < 8; ++p) {
            float dx = px[p] - cx, dy = py[p] - cy, dz = pz[p] - cz;
            float d  = __fadd_rn(__fadd_rn(__fmul_rn(dx,dx), __fmul_rn(dy,dy)), __fmul_rn(dz,dz));
            float nd = fminf(dist[p], d);
            dist[p] = nd;
            ull pk = ((ull)__float_as_uint(nd) << 32) | (ull)njc[p];
            if (pk > best) best = pk;
        }
        // DPP wave-64 max reduction -> lane 63 (VALU pipe)
        {
            uint hi = (uint)(best >> 32), lo = (uint)best;
            #define FPS_DPP(CTRL) { \
                uint h2 = (uint)__builtin_amdgcn_update_dpp((int)hi, (int)hi, CTRL, 0xF, 0xF, false); \
                uint l2 = (uint)__builtin_amdgcn_update_dpp((int)lo, (int)lo, CTRL, 0xF, 0xF, false); \
                ull o = ((ull)h2 << 32) | (ull)l2; \
                if (o > best) { best = o; hi = h2; lo = l2; } }
            FPS_DPP(0x111)   // row_shr:1
            FPS_DPP(0x112)   // row_shr:2
            FPS_DPP(0x114)   // row_shr:4
            FPS_DPP(0x118)   // row_shr:8
            FPS_DPP(0x142)   // row_bcast:15
            FPS_DPP(0x143)   // row_bcast:31
            #undef FPS_DPP
        }
        if ((lt & 63) == 63) atomicMax(&slot[cur], best);
        int nxt = cur + 1; if (nxt == 3) nxt = 0;
        if (lt == 0) slot[nxt] = 0ull;   // slot last read 2 barriers ago (safe)
        __syncthreads();
        ull pk = slot[cur];
        int last = (int)(~(uint)pk);     // lo32 = ~j exactly
        float4 c4 = lc[last];
        cx = c4.x; cy = c4.y; cz = c4.z;
        cur = nxt;
    }
}

// ---------------- ball query: one wave per center ----------------
__global__ __launch_bounds__(256) void ballq_kernel(const float* __restrict__ xyz,
                                                    const float* __restrict__ new_xyz,
                                                    int* __restrict__ idx) {
    const int wid  = (blockIdx.x * 256 + threadIdx.x) >> 6;   // center id
    const int lane = threadIdx.x & 63;
    const int b = wid >> 10;
    const float* xb = xyz + (size_t)b * N * 3;
    const float cx = new_xyz[(size_t)wid*3+0];
    const float cy = new_xyz[(size_t)wid*3+1];
    const float cz = new_xyz[(size_t)wid*3+2];
    int* ob = idx + (size_t)wid * K;

    const float R2 = 0.04f;  // float32(0.2*0.2) per JAX weak-type demotion
    int total = 0;
    int first = 0;
    bool gotfirst = false;
    for (int c0 = 0; c0 < N; c0 += 64) {
        const int j = c0 + lane;
        float dx = cx - xb[j*3+0];
        float dy = cy - xb[j*3+1];
        float dz = cz - xb[j*3+2];
        float d2 = __fadd_rn(__fadd_rn(__fmul_rn(dx,dx), __fmul_rn(dy,dy)), __fmul_rn(dz,dz));
        bool inr = d2 < R2;
        unsigned long long bal = __ballot(inr);
        if (bal) {
            if (!gotfirst) { first = c0 + __builtin_ctzll(bal); gotfirst = true; }
            int rank = __popcll(bal & ((1ull << lane) - 1ull));
            int pos = total + rank;
            if (inr && pos < K) ob[pos] = j;
            total += __popcll(bal);
            if (total >= K) break;
        }
    }
    for (int p2 = total + lane; p2 < K; p2 += 64) ob[p2] = first;
}

// ---------------- conv0: LDS-tiled GEMM, 128 positions x 64 outputs, K=68 ----
// xt[k][p]: rows 0-2 rel coords, 3..66 = feat[0..63], 67 = zero pad.
// wt[k][o]: wt[k][o] = w0[o*67+k] (k<67), row 67 = 0.
// Thread (po=t>>3, og=t&7): 4 positions x 8 outputs in registers.
__global__ __launch_bounds__(256) void conv0_kernel(const float* __restrict__ xyz,
                                                    const float* __restrict__ new_xyz,
                                                    const float* __restrict__ featT,
                                                    const int* __restrict__ idx,
                                                    const float* __restrict__ w0,
                                                    const float* __restrict__ b0,
                                                    ushort* __restrict__ x0) {
    __shared__ float xt[68][128];   // 34.8 KB
    __shared__ float wt[68][64];    // 17.4 KB
    const int t  = threadIdx.x;
    const int p0 = blockIdx.x * 128;

    // stage weights (+ zero pad row)
    for (int i = t; i < 68*64; i += 256) {
        const int k = i >> 6, o = i & 63;
        wt[k][o] = (k < 67) ? w0[(size_t)o*67 + k] : 0.f;
    }
    // stage coords rows (threads 0..127) / zero pad row (threads 128..255)
    if (t < 128) {
        const int p  = p0 + t;
        const int bs = p >> 5;
        const int b  = p >> 15;
        const int j  = idx[p];
        const float* xp = xyz + ((size_t)b*N + (size_t)j)*3;
        xt[0][t] = xp[0] - new_xyz[(size_t)bs*3+0];
        xt[1][t] = xp[1] - new_xyz[(size_t)bs*3+1];
        xt[2][t] = xp[2] - new_xyz[(size_t)bs*3+2];
    } else {
        xt[67][t-128] = 0.f;
    }
    // stage features: unit i -> (q = i>>7, p = i&127); lanes span positions
    // for fixed q -> LDS row-contiguous writes (conflict-free)
    #pragma unroll
    for (int r = 0; r < 8; ++r) {
        const int i = t + (r << 8);
        const int q = i >> 7;           // 0..15
        const int p = i & 127;
        const int gp = p0 + p;
        const int b  = gp >> 15;
        const int j  = idx[gp];
        const float4 v = *(const float4*)(featT + ((((size_t)b*N + j) << 6) + (q << 2)));
        xt[3 + 4*q + 0][p] = v.x;
        xt[3 + 4*q + 1][p] = v.y;
        xt[3 + 4*q + 2][p] = v.z;
        xt[3 + 4*q + 3][p] = v.w;
    }
    __syncthreads();

    const int po = t >> 3;   // 0..31 -> positions po*4 .. po*4+3
    const int og = t & 7;    // outputs og*8 .. og*8+7
    float a[4][8];
    #pragma unroll
    for (int i = 0; i < 8; ++i) {
        const float bv = b0[og*8 + i];
        a[0][i] = bv; a[1][i] = bv; a[2][i] = bv; a[3][i] = bv;
    }
    #pragma unroll 2
    for (int k = 0; k < 68; ++k) {
        const float4 xv = *(const float4*)&xt[k][po*4];
        float w[8];
        *(float4*)&w[0] = *(const float4*)&wt[k][og*8];
        *(float4*)&w[4] = *(const float4*)&wt[k][og*8+4];
        #pragma unroll
        for (int i = 0; i < 8; ++i) {
            a[0][i] = fmaf(w[i], xv.x, a[0][i]);
            a[1][i] = fmaf(w[i], xv.y, a[1][i]);
            a[2][i] = fmaf(w[i], xv.z, a[2][i]);
            a[3][i] = fmaf(w[i], xv.w, a[3][i]);
        }
    }
    // store: 8 outputs x 4 consecutive positions (uint2 = 4 halfs)
    #pragma unroll
    for (int i = 0; i < 8; ++i) {
        const int o = og*8 + i;
        uint2 wd;
        wd.x = (uint)f2h(a[0][i]) | ((uint)f2h(a[1][i]) << 16);
        wd.y = (uint)f2h(a[2][i]) | ((uint)f2h(a[3][i]) << 16);
        *(uint2*)(x0 + (size_t)o*NPOS + p0 + po*4) = wd;
    }
}

// ---------------- per-channel sum / sumsq (C=64 layout, stride 64) ----------------
__global__ __launch_bounds__(256) void stats_kernel(const ushort* __restrict__ x,
                                                    float* __restrict__ st) {
    const int c = blockIdx.y;   // 0..63
    const uint2* xr = (const uint2*)(x + (size_t)c * NPOS);
    const int t = blockIdx.x * 256 + threadIdx.x;   // 0..8191
    float s = 0.f, q = 0.f;
    #pragma unroll
    for (int i = 0; i < 16; ++i) {
        uint2 u = xr[(size_t)i*8192 + t];
        float v0 = h2f((ushort)(u.x & 0xffff));
        float v1 = h2f((ushort)(u.x >> 16));
        float v2 = h2f((ushort)(u.y & 0xffff));
        float v3 = h2f((ushort)(u.y >> 16));
        s += v0 + v1 + v2 + v3;
        q += v0*v0 + v1*v1 + v2*v2 + v3*v3;
    }
    #pragma unroll
    for (int off = 32; off; off >>= 1) { s += __shfl_xor(s, off); q += __shfl_xor(q, off); }
    __shared__ float ls[4], lq[4];
    const int w = threadIdx.x >> 6;
    if ((threadIdx.x & 63) == 0) { ls[w] = s; lq[w] = q; }
    __syncthreads();
    if (threadIdx.x == 0) {
        s = ls[0]+ls[1]+ls[2]+ls[3];
        q = lq[0]+lq[1]+lq[2]+lq[3];
        atomicAdd(&st[c], s);
        atomicAdd(&st[64+c], q);
    }
}

// ---------------- fold BN into scale/shift (C=64) ----------------
__global__ void finalize_kernel(float* st, const float* __restrict__ g,
                                const float* __restrict__ be) {
    const int c = threadIdx.x;
    if (c < 64) {
        const float invn = 1.0f / (float)NPOS;
        float mean = st[c] * invn;
        float var  = st[64+c] * invn - mean*mean;
        float inv  = 1.0f / sqrtf(var + 1e-5f);
        float sc   = g[c] * inv;
        st[128+c] = sc;
        st[192+c] = fmaf(-mean, sc, be[c]);
    }
}

// ---------------- middle conv: normalize(prev)+relu then 64->64 ----------------
__global__ __launch_bounds__(256) void conv_mid_kernel(const ushort* __restrict__ xin,
                                                       const float* __restrict__ st,   // prev layer stats
                                                       const float* __restrict__ w,
                                                       const float* __restrict__ bias,
                                                       ushort* __restrict__ xout,
                                                       int wbase) {
    const int pp = blockIdx.x * 256 + threadIdx.x;   // pair index < NPAIR
    const float* scale = st + 128;
    const float* shift = st + 192;
    float a0[64], a1[64];
    #pragma unroll
    for (int o = 0; o < 64; ++o) { a0[o] = bias[wbase+o]; a1[o] = a0[o]; }
    const uint* xr = (const uint*)xin;
    #pragma unroll 4
    for (int c = 0; c < 64; ++c) {
        uint u = xr[(size_t)c * NPAIR + pp];
        float v0 = h2f((ushort)(u & 0xffff));
        float v1 = h2f((ushort)(u >> 16));
        float sc = scale[c], sh = shift[c];
        v0 = fmaxf(0.0f, fmaf(v0, sc, sh));
        v1 = fmaxf(0.0f, fmaf(v1, sc, sh));
        const float* wr = w + (size_t)wbase * 64 + c;
        #pragma unroll
        for (int o = 0; o < 64; ++o) {
            float wv = wr[o*64];
            a0[o] = fmaf(wv, v0, a0[o]);
            a1[o] = fmaf(wv, v1, a1[o]);
        }
    }
    uint* orow = (uint*)xout;
    #pragma unroll
    for (int o = 0; o < 64; ++o) {
        uint wd = (uint)f2h(a0[o]) | ((uint)f2h(a1[o]) << 16);
        orow[(size_t)o * NPAIR + pp] = wd;
    }
}

// ---------------- max-pool over K with BN+relu (64-channel half) ----------------
__global__ __launch_bounds__(256) void maxpool_kernel(const ushort* __restrict__ xh,
                                                      const float* __restrict__ st,   // this half's stats
                                                      float* __restrict__ out,
                                                      int cbase) {
    const int gid = blockIdx.x * 256 + threadIdx.x;   // < 64*16384
    const int c  = gid >> 14;       // 0..63 local channel
    const int bs = gid & 16383;
    const float sc = st[128 + c], sh = st[192 + c];
    const uint* xr = (const uint*)(xh + (size_t)c * NPOS + (size_t)bs * K);
    float m = -3.4e38f;
    #pragma unroll
    for (int i = 0; i < 16; ++i) {
        uint u = xr[i];
        m = fmaxf(m, fmaf(h2f((ushort)(u & 0xffff)), sc, sh));
        m = fmaxf(m, fmaf(h2f((ushort)(u >> 16)),    sc, sh));
    }
    m = fmaxf(m, 0.0f);   // relu(max) == max(relu) (monotone)
    const int b = bs >> 10, s = bs & 1023;
    out[((size_t)b*128 + cbase + c)*1024 + s] = m;
}

extern "C" void kernel_launch(void* const* d_in, const int* in_sizes, int n_in,
                              void* d_out, int out_size, void* d_ws, size_t ws_size,
                              hipStream_t stream) {
    const float* xyz      = (const float*)d_in[0];
    const float* features = (const float*)d_in[1];
    const float* w0 = (const float*)d_in[2];
    const float* b0 = (const float*)d_in[3];
    const float* g0 = (const float*)d_in[4];
    const float* be0= (const float*)d_in[5];
    const float* w1 = (const float*)d_in[6];
    const float* b1 = (const float*)d_in[7];
    const float* g1 = (const float*)d_in[8];
    const float* be1= (const float*)d_in[9];
    const float* w2 = (const float*)d_in[10];
    const float* b2 = (const float*)d_in[11];
    const float* g2 = (const float*)d_in[12];
    const float* be2= (const float*)d_in[13];

    float* out      = (float*)d_out;
    float* new_xyz  = out;              // (B,S,3)
    float* new_feat = out + (size_t)B*S*3;

    char* ws = (char*)d_ws;
    int*    idx   = (int*)ws;
    float*  featT = (float*)(ws + (2u<<20));
    float*  stats = (float*)(ws + (18u<<20));
    ushort* x0    = (ushort*)(ws + (18u<<20) + (1u<<16));
    ushort* x1    = x0 + (size_t)64 * NPOS;       // +64MB
    ushort* xh    = x0;                           // layer-2 half buffer aliases x0
    float* st0  = stats;            // C=64: sum,sumsq,scale,shift
    float* st1  = stats + 256;
    float* st2a = stats + 512;
    float* st2b = stats + 768;

    hipMemsetAsync(stats, 0, 1024 * sizeof(float), stream);

    fps_tr_kernel<<<16 + 512, 512, 0, stream>>>(xyz, new_xyz, features, featT);
    ballq_kernel<<<(B*S)/4, 256, 0, stream>>>(xyz, new_xyz, idx);
    conv0_kernel<<<NPOS/128, 256, 0, stream>>>(xyz, new_xyz, featT, idx, w0, b0, x0);

    stats_kernel<<<dim3(32, 64), 256, 0, stream>>>(x0, st0);
    finalize_kernel<<<1, 64, 0, stream>>>(st0, g0, be0);
    conv_mid_kernel<<<NPAIR/256, 256, 0, stream>>>(x0, st0, w1, b1, x1, 0);

    stats_kernel<<<dim3(32, 64), 256, 0, stream>>>(x1, st1);
    finalize_kernel<<<1, 64, 0, stream>>>(st1, g1, be1);

    // layer 2, half 0 (output channels 0..63) — xh aliases x0 (dead now)
    conv_mid_kernel<<<NPAIR/256, 256, 0, stream>>>(x1, st1, w2, b2, xh, 0);
    stats_kernel<<<dim3(32, 64), 256, 0, stream>>>(xh, st2a);
    finalize_kernel<<<1, 64, 0, stream>>>(st2a, g2, be2);
    maxpool_kernel<<<(64*B*S)/256, 256, 0, stream>>>(xh, st2a, new_feat, 0);

    // layer 2, half 1 (output channels 64..127)
    conv_mid_kernel<<<NPAIR/256, 256, 0, stream>>>(x1, st1, w2, b2, xh, 64);
    stats_kernel<<<dim3(32, 64), 256, 0, stream>>>(xh, st2b);
    finalize_kernel<<<1, 64, 0, stream>>>(st2b, g2 + 64, be2 + 64);
    maxpool_kernel<<<(64*B*S)/256, 256, 0, stream>>>(xh, st2b, new_feat, 64);
}